// Round 4
// baseline (725.744 us; speedup 1.0000x reference)
//
#include <hip/hip_runtime.h>
#include <math.h>

#define NROWS 65536
#define BN_EPS 1e-5f

// ---- workspace layout (floats) ----
// OFF_REC     : packed per-feature record rec[f][84]                    [5376]
//               0..15 U=W1+W2 | 16..31 B1 | 32..47 B2 | 48..55 A1
//               56..63 A2 | 64..71 A3 | 72 QU 73 QB1 74 QB2 75 2QUB1
//               76 2QUB2 77 2QB1B2 | 78 w1 79 b1 80 b2 | 81..83 pad
// OFF_T       : atomic totals T[96]: 0..63 Xc colsum, 64..71 sum h_j,
//               72..79 sum h_j^2
// OFF_PARTIAL : per-row partial                                          [65536]
// OFF_H       : h[row*8+j]                                               [524288]
#define OFF_REC     0
#define OFF_T       5376
#define OFF_PARTIAL 5472
#define OFF_H       71008

// 65 blocks x 64 threads: block f<64 builds rec[f][*]; block 64 zeroes T.
__global__ __launch_bounds__(64) void precompute_kernel(
    const float* __restrict__ W1, const float* __restrict__ B1,
    const float* __restrict__ W2, const float* __restrict__ B2,
    const float* __restrict__ lin1_w, const float* __restrict__ w1,
    const float* __restrict__ b1, const float* __restrict__ b2,
    float* __restrict__ rec, float* __restrict__ T)
{
    int f = blockIdx.x, t = threadIdx.x;
    if (f == 64) {
        if (t < 96) T[t] = 0.f;
        return;
    }
    __shared__ float u[16], x[16], y[16];
    if (t < 16) {
        float uu = W1[f * 16 + t] + W2[f * 16 + t];
        float xx = B1[f * 16 + t];
        float yy = B2[f * 16 + t];
        u[t] = uu; x[t] = xx; y[t] = yy;
        rec[f * 84 + t]      = uu;
        rec[f * 84 + 16 + t] = xx;
        rec[f * 84 + 32 + t] = yy;
    }
    __syncthreads();
    if (t < 24) {
        int j = t & 7, which = t >> 3;
        const float* src = (which == 0) ? u : (which == 1) ? x : y;
        const float* lw = lin1_w + j * 1024 + f * 16;
        float acc = 0.f;
#pragma unroll
        for (int e = 0; e < 16; e++) acc = fmaf(src[e], lw[e], acc);
        rec[f * 84 + 48 + which * 8 + j] = acc;
    } else if (t < 30) {
        int q = t - 24;
        const float* s1 = (q == 0 || q == 3 || q == 4) ? u : (q == 1 || q == 5) ? x : y;
        const float* s2 = (q == 0) ? u : (q == 1 || q == 3) ? x : y;
        float acc = 0.f;
#pragma unroll
        for (int e = 0; e < 16; e++) acc = fmaf(s1[e], s2[e], acc);
        rec[f * 84 + 72 + q] = (q < 3 ? 1.f : 2.f) * acc;
    } else if (t == 30) {
        rec[f * 84 + 78] = w1[f];
        rec[f * 84 + 79] = b1[f];
        rec[f * 84 + 80] = b2[f];
        rec[f * 84 + 81] = 0.f;
        rec[f * 84 + 82] = 0.f;
        rec[f * 84 + 83] = 0.f;
    }
}

// 512 blocks x 256 threads. Block = 128 rows (2 chunks of 64, lane = row).
// Wave w owns f-quarter w; its table quarter streams via wave-uniform LDS
// broadcasts (same-address ds_read = conflict-free, lgkmcnt-pipelined).
__global__ __launch_bounds__(256, 3) void main_kernel(
    const float* __restrict__ Xa, const float* __restrict__ Xc,
    const float* __restrict__ rec, const float* __restrict__ lin1_b,
    float* __restrict__ ws_partial, float* __restrict__ ws_h,
    float* __restrict__ T)
{
    // aliased: [0,5376) rec staging during phase 1; then cmb[4][64][29]
    __shared__ __align__(16) float smem[7424];

    int tid  = threadIdx.x;
    int lane = tid & 63;
    int wv   = tid >> 6;
    int blk  = blockIdx.x;
    int f0   = wv * 16;

    // stage rec -> LDS (coalesced float4)
    {
        const float4* src = (const float4*)rec;
        float4* dst = (float4*)smem;
        for (int i = tid; i < 1344; i += 256) dst[i] = src[i];
    }
    __syncthreads();

    const float* recw = smem + f0 * 84;

    size_t r0 = ((size_t)blk * 128 + lane) * 64;
    const float4* pa0 = (const float4*)(Xa + r0);
    const float4* pc0 = (const float4*)(Xc + r0);
    const float4* pa1 = (const float4*)(Xa + r0 + 64 * 64);
    const float4* pc1 = (const float4*)(Xc + r0 + 64 * 64);
    int ko = wv * 4;

    float s0[16], s1[16], h0[8], h1[8], cs[16];
#pragma unroll
    for (int e = 0; e < 16; e++) { s0[e] = 0.f; s1[e] = 0.f; }
#pragma unroll
    for (int j = 0; j < 8; j++) { h0[j] = 0.f; h1[j] = 0.f; }
    float p1a = 0.f, p1b = 0.f, p2a0 = 0.f, p2a1 = 0.f, q0 = 0.f, q1 = 0.f;

#pragma unroll
    for (int k = 0; k < 4; k++) {
        float4 A0 = pa0[ko + k], C0 = pc0[ko + k];
        float4 A1 = pa1[ko + k], C1 = pc1[ko + k];
        float av0[4] = {A0.x, A0.y, A0.z, A0.w};
        float cv0[4] = {C0.x, C0.y, C0.z, C0.w};
        float av1[4] = {A1.x, A1.y, A1.z, A1.w};
        float cv1[4] = {C1.x, C1.y, C1.z, C1.w};
#pragma unroll
        for (int uu = 0; uu < 4; uu++) {
            int i = k * 4 + uu;
            const float* r = recw + i * 84;   // wave-uniform -> broadcast
            {
                float a = av0[uu], c = cv0[uu], pp = a * c;
                p1a  = fmaf(fmaf(r[78], a, r[79]), c, p1a);
                p2a0 = fmaf(a, r[80], p2a0);
                q0 = fmaf(pp * pp, r[72], q0);
                q0 = fmaf(c * c,   r[73], q0);
                q0 = fmaf(a * a,   r[74], q0);
                q0 = fmaf(pp * c,  r[75], q0);
                q0 = fmaf(pp * a,  r[76], q0);
                q0 = fmaf(pp,      r[77], q0);
#pragma unroll
                for (int e = 0; e < 16; e++)
                    s0[e] = fmaf(pp, r[e], fmaf(c, r[16+e], fmaf(a, r[32+e], s0[e])));
#pragma unroll
                for (int j = 0; j < 8; j++)
                    h0[j] = fmaf(pp, r[48+j], fmaf(c, r[56+j], fmaf(a, r[64+j], h0[j])));
            }
            {
                float a = av1[uu], c = cv1[uu], pp = a * c;
                p1b  = fmaf(fmaf(r[78], a, r[79]), c, p1b);
                p2a1 = fmaf(a, r[80], p2a1);
                q1 = fmaf(pp * pp, r[72], q1);
                q1 = fmaf(c * c,   r[73], q1);
                q1 = fmaf(a * a,   r[74], q1);
                q1 = fmaf(pp * c,  r[75], q1);
                q1 = fmaf(pp * a,  r[76], q1);
                q1 = fmaf(pp,      r[77], q1);
#pragma unroll
                for (int e = 0; e < 16; e++)
                    s1[e] = fmaf(pp, r[e], fmaf(c, r[16+e], fmaf(a, r[32+e], s1[e])));
#pragma unroll
                for (int j = 0; j < 8; j++)
                    h1[j] = fmaf(pp, r[48+j], fmaf(c, r[56+j], fmaf(a, r[64+j], h1[j])));
            }
            cs[i] = cv0[uu] + cv1[uu];
        }
    }

    // Xc column sums -> atomic totals
    {
#pragma unroll
        for (int off = 1; off < 64; off <<= 1) {
#pragma unroll
            for (int i = 0; i < 16; i++) cs[i] += __shfl_xor(cs[i], off);
        }
        if (lane == 0) {
#pragma unroll
            for (int i = 0; i < 16; i++)
                unsafeAtomicAdd(&T[f0 + i], cs[i]);
        }
    }

    // cross-wave combine, chunk by chunk; BN partials accumulated
    float bn[16];
#pragma unroll
    for (int i = 0; i < 16; i++) bn[i] = 0.f;

#pragma unroll
    for (int g = 0; g < 2; g++) {
        __syncthreads();   // also retires rec reads (g==0) before aliasing
        float* cmb = smem + (wv * 64 + lane) * 29;
#pragma unroll
        for (int e = 0; e < 16; e++) cmb[e] = g ? s1[e] : s0[e];
#pragma unroll
        for (int j = 0; j < 8; j++) cmb[16 + j] = g ? h1[j] : h0[j];
        cmb[24] = g ? p1b : p1a;
        cmb[25] = g ? p2a1 : p2a0;
        cmb[26] = g ? q1 : q0;
        __syncthreads();

        if (tid < 64) {
            float S[16], H[8], P1 = 0.f, P2 = 0.f, Q = 0.f;
#pragma unroll
            for (int e = 0; e < 16; e++) S[e] = 0.f;
#pragma unroll
            for (int j = 0; j < 8; j++) H[j] = 0.f;
#pragma unroll
            for (int w = 0; w < 4; w++) {
                const float* c2 = smem + (w * 64 + tid) * 29;
#pragma unroll
                for (int e = 0; e < 16; e++) S[e] += c2[e];
#pragma unroll
                for (int j = 0; j < 8; j++) H[j] += c2[16 + j];
                P1 += c2[24];
                P2 += c2[25];
                Q  += c2[26];
            }
#pragma unroll
            for (int j = 0; j < 8; j++) H[j] += lin1_b[j];

            float ss = 0.f;
#pragma unroll
            for (int e = 0; e < 16; e++) ss = fmaf(S[e], S[e], ss);
            int rr = blk * 128 + g * 64 + tid;
            ws_partial[rr] = (P1 + P2) * (1.f / 64.f) + (ss - Q) * (0.5f / 16.f);
            *(float4*)(ws_h + (size_t)rr * 8)     = make_float4(H[0], H[1], H[2], H[3]);
            *(float4*)(ws_h + (size_t)rr * 8 + 4) = make_float4(H[4], H[5], H[6], H[7]);
#pragma unroll
            for (int j = 0; j < 8; j++) {
                bn[j]     += H[j];
                bn[8 + j] += H[j] * H[j];
            }
        }
    }

    if (tid < 64) {
#pragma unroll
        for (int off = 1; off < 64; off <<= 1) {
#pragma unroll
            for (int i = 0; i < 16; i++) bn[i] += __shfl_xor(bn[i], off);
        }
        if (tid == 0) {
#pragma unroll
            for (int i = 0; i < 16; i++)
                unsafeAtomicAdd(&T[64 + i], bn[i]);
        }
    }
}

// 256 blocks x 256 threads: one row per thread.
__global__ __launch_bounds__(256) void final_kernel(
    const float* __restrict__ Xa, const float* __restrict__ w2,
    const float* __restrict__ gamma, const float* __restrict__ beta,
    const float* __restrict__ lin2_w, const float* __restrict__ lin2_b,
    const float* __restrict__ T, const float* __restrict__ ws_partial,
    const float* __restrict__ ws_h, float* __restrict__ out)
{
    __shared__ float sg[64], sScale[8], sShift[8], sL2w[32], sL2b[4];
    int tid = threadIdx.x;
    if (tid < 64) {
        sg[tid] = w2[tid] * (T[tid] * (1.f / 65536.f));
    } else if (tid < 72) {
        int j = tid - 64;
        float mu  = T[64 + j] * (1.f / 65536.f);
        float var = T[72 + j] * (1.f / 65536.f) - mu * mu;
        float sc = gamma[j] / sqrtf(var + BN_EPS);
        sScale[j] = sc;
        sShift[j] = beta[j] - mu * sc;
    } else if (tid < 104) {
        sL2w[tid - 72] = lin2_w[tid - 72];
    } else if (tid < 108) {
        sL2b[tid - 104] = lin2_b[tid - 104];
    }
    __syncthreads();

    int row = blockIdx.x * 256 + tid;
    const float4* xa4 = (const float4*)(Xa + (size_t)row * 64);
    float p2b = 0.f;
#pragma unroll
    for (int k = 0; k < 16; k++) {
        float4 vv = xa4[k];
        p2b += vv.x * sg[k * 4] + vv.y * sg[k * 4 + 1]
             + vv.z * sg[k * 4 + 2] + vv.w * sg[k * 4 + 3];
    }
    float4 h0 = *(const float4*)(ws_h + (size_t)row * 8);
    float4 h1 = *(const float4*)(ws_h + (size_t)row * 8 + 4);
    float hv[8] = {h0.x, h0.y, h0.z, h0.w, h1.x, h1.y, h1.z, h1.w};
    float hn[8];
#pragma unroll
    for (int j = 0; j < 8; j++)
        hn[j] = tanhf(hv[j] * sScale[j] + sShift[j]);
    float dm = 0.f;
#pragma unroll
    for (int k2 = 0; k2 < 4; k2++) {
        float o = sL2b[k2];
#pragma unroll
        for (int j = 0; j < 8; j++) o = fmaf(hn[j], sL2w[k2 * 8 + j], o);
        dm += o;
    }
    out[row] = ws_partial[row] + p2b * (1.f / 64.f) + dm * 0.25f;
}

extern "C" void kernel_launch(void* const* d_in, const int* in_sizes, int n_in,
                              void* d_out, int out_size, void* d_ws, size_t ws_size,
                              hipStream_t stream) {
    const float* Xa        = (const float*)d_in[0];
    const float* Xc        = (const float*)d_in[1];
    const float* w1        = (const float*)d_in[2];
    const float* b1        = (const float*)d_in[3];
    const float* w2        = (const float*)d_in[4];
    const float* b2        = (const float*)d_in[5];
    const float* W1        = (const float*)d_in[6];
    const float* B1        = (const float*)d_in[7];
    const float* W2        = (const float*)d_in[8];
    const float* B2        = (const float*)d_in[9];
    const float* lin1_w    = (const float*)d_in[10];
    const float* lin1_b    = (const float*)d_in[11];
    const float* bn1_gamma = (const float*)d_in[12];
    const float* bn1_beta  = (const float*)d_in[13];
    const float* lin2_w    = (const float*)d_in[14];
    const float* lin2_b    = (const float*)d_in[15];

    float* ws  = (float*)d_ws;
    float* out = (float*)d_out;

    float* ws_rec     = ws + OFF_REC;
    float* ws_T       = ws + OFF_T;
    float* ws_partial = ws + OFF_PARTIAL;
    float* ws_h       = ws + OFF_H;

    precompute_kernel<<<65, 64, 0, stream>>>(W1, B1, W2, B2, lin1_w,
                                             w1, b1, b2, ws_rec, ws_T);
    main_kernel<<<512, 256, 0, stream>>>(Xa, Xc, ws_rec, lin1_b,
                                         ws_partial, ws_h, ws_T);
    final_kernel<<<256, 256, 0, stream>>>(Xa, w2, bn1_gamma, bn1_beta,
                                          lin2_w, lin2_b, ws_T,
                                          ws_partial, ws_h, out);
}